// Round 6
// baseline (848.512 us; speedup 1.0000x reference)
//
#include <hip/hip_runtime.h>
#include <math.h>

#define B_   64
#define T_   200
#define DM   256
#define DI   512
#define NH   16
#define HD   32
#define DSZ  16
#define CD   544
#define DIP  1072
#define M_TOT (B_*T_)   // 12800
#define NCH_ 129
#define KENC 192        // encoder K padded (129 -> 192, 2*192 = 384 = 6*64)
#define NCHUNK 8
#define CLEN  25        // 200 / 8

typedef unsigned short u16;
typedef unsigned int u32;
typedef _Float16 f16;
typedef __attribute__((ext_vector_type(8))) _Float16 half8;  // 8 f16 (4 VGPRs)
typedef __attribute__((ext_vector_type(4))) short short4v;   // 4 u16
typedef __attribute__((ext_vector_type(4))) float f32x4;

// ---------------- helpers ----------------------------------------------------
__device__ __forceinline__ float wave_sum(float v) {
    #pragma unroll
    for (int off = 32; off > 0; off >>= 1) v += __shfl_xor(v, off);
    return v;
}
__device__ __forceinline__ void split_f16(float a, u16& hi, u16& lo) {
    f16 h = (f16)a;
    f16 l = (f16)(a - (float)h);
    hi = __builtin_bit_cast(u16, h);
    lo = __builtin_bit_cast(u16, l);
}
__device__ __forceinline__ u16 f16bits(float a) {
    f16 h = (f16)a;
    return __builtin_bit_cast(u16, h);
}

// ---------------- emb mean over channels ------------------------------------
__global__ void emb_mean_k(const float* __restrict__ emb, float* __restrict__ em) {
    int d = threadIdx.x;
    float s = 0.f;
    for (int c = 0; c < NCH_; ++c) s += emb[c * DM + d];
    em[d] = s * (1.f / NCH_);
}

// ---------------- encoder dwconv (K=3) -> A2 [M x 2*KENC] (hi|lo) -----------
__global__ void xsA2_k(const float* __restrict__ x, const float* __restrict__ w,
                       const float* __restrict__ b, u16* __restrict__ A2) {
    int idx = blockIdx.x * blockDim.x + threadIdx.x;
    if (idx >= M_TOT * KENC) return;
    int c = idx % KENC;
    int m = idx / KENC;
    float acc = 0.f;
    if (c < NCH_) {
        int t = m % T_;
        int bb = m / T_;
        const float* xr = x + (size_t)(bb * NCH_ + c) * T_;
        acc = b[c];
        if (t > 0)      acc += w[c*3+0] * xr[t-1];
        acc += w[c*3+1] * xr[t];
        if (t < T_-1)   acc += w[c*3+2] * xr[t+1];
    }
    u16 hi, lo; split_f16(acc, hi, lo);
    u16* row = A2 + (size_t)m * (2*KENC);
    row[c] = hi; row[KENC + c] = lo;
}

// ---------------- pack weights fp32 -> f16 [hi | hi], L layers --------------
__global__ void pack_b2_k(const float* __restrict__ W, u16* __restrict__ B2,
                          int L, int N, int Npad, int Kreal, int K) {
    int idx = blockIdx.x * blockDim.x + threadIdx.x;
    if (idx >= L * Npad * K) return;
    int k = idx % K;
    int n = (idx / K) % Npad;
    int l = idx / (K * Npad);
    u16 hi = 0;
    if (n < N && k < Kreal)
        hi = f16bits(W[((size_t)l * N + n) * Kreal + k]);
    u16* row = B2 + ((size_t)l * Npad + n) * 2 * K;
    row[k] = hi;
    row[K + k] = hi;
}

// ---------------- MFMA f16 GEMM: C = A2 * B2^T, 128x128 tile, XCD swizzle ---
// grid: 1D nbx*nby blocks, 256 thr (4 waves 2x2, each wave 64x64 output)
__global__ __launch_bounds__(256) void gemm_mfma(const u16* __restrict__ A2,
                                                 const u16* __restrict__ B2,
                                                 float* __restrict__ C,
                                                 int K2, int ldc, int Nreal,
                                                 int nbx) {
    __shared__ u16 As[128 * 64];
    __shared__ u16 Bs[128 * 64];
    // bijective XCD-chunked swizzle (m204)
    int nwg = gridDim.x;
    int lin = blockIdx.x;
    int q = nwg >> 3, r = nwg & 7;
    int xcd = lin & 7, idx = lin >> 3;
    int wg = ((xcd < r) ? xcd * (q + 1) : r * (q + 1) + (xcd - r) * q) + idx;
    int bx = wg % nbx, by = wg / nbx;

    int tid = threadIdx.x;
    int lane = tid & 63;
    int wave = tid >> 6;
    int wr = wave >> 1;
    int wc = wave & 1;
    int bm = by * 128;
    int bn = bx * 128;

    f32x4 acc[4][4] = {};
    const size_t ldA = (size_t)K2 * 2;   // bytes per row

    for (int k0 = 0; k0 < K2; k0 += 64) {
        #pragma unroll
        for (int c = 0; c < 4; ++c) {
            int o = c * 4096 + tid * 16;
            int row = o >> 7;
            int slot = (o >> 4) & 7;
            int sslot = slot ^ (row & 7);
            const char* src = (const char*)A2 + (size_t)(bm + row) * ldA
                              + (size_t)k0 * 2 + sslot * 16;
            __builtin_amdgcn_global_load_lds(
                (const __attribute__((address_space(1))) u32*)src,
                (__attribute__((address_space(3))) u32*)((char*)As + o),
                16, 0, 0);
        }
        #pragma unroll
        for (int c = 0; c < 4; ++c) {
            int o = c * 4096 + tid * 16;
            int row = o >> 7;
            int slot = (o >> 4) & 7;
            int sslot = slot ^ (row & 7);
            const char* src = (const char*)B2 + (size_t)(bn + row) * ldA
                              + (size_t)k0 * 2 + sslot * 16;
            __builtin_amdgcn_global_load_lds(
                (const __attribute__((address_space(1))) u32*)src,
                (__attribute__((address_space(3))) u32*)((char*)Bs + o),
                16, 0, 0);
        }
        __syncthreads();
        #pragma unroll
        for (int kk = 0; kk < 2; ++kk) {
            int lslot = kk * 4 + (lane >> 4);
            half8 afr[4], bfr[4];
            #pragma unroll
            for (int n = 0; n < 4; ++n) {
                int row = wc * 64 + n * 16 + (lane & 15);
                int pslot = lslot ^ (row & 7);
                bfr[n] = *(const half8*)((const char*)Bs + row * 128 + pslot * 16);
            }
            #pragma unroll
            for (int m = 0; m < 4; ++m) {
                int row = wr * 64 + m * 16 + (lane & 15);
                int pslot = lslot ^ (row & 7);
                afr[m] = *(const half8*)((const char*)As + row * 128 + pslot * 16);
            }
            #pragma unroll
            for (int m = 0; m < 4; ++m)
                #pragma unroll
                for (int n = 0; n < 4; ++n)
                    acc[m][n] = __builtin_amdgcn_mfma_f32_16x16x32_f16(
                        afr[m], bfr[n], acc[m][n], 0, 0, 0);
        }
        __syncthreads();
    }

    int crow0 = bm + wr * 64;
    int ccol0 = bn + wc * 64;
    #pragma unroll
    for (int m = 0; m < 4; ++m) {
        #pragma unroll
        for (int n = 0; n < 4; ++n) {
            int col = ccol0 + n * 16 + (lane & 15);
            if (col < Nreal) {
                #pragma unroll
                for (int j = 0; j < 4; ++j) {
                    int rrow = crow0 + m * 16 + (lane >> 4) * 4 + j;
                    C[(size_t)rrow * ldc + col] = acc[m][n][j];
                }
            }
        }
    }
}

// ---------------- encoder LN (wave/row): h += mb+em; LN; write h + A2 -------
__global__ __launch_bounds__(256) void enc_ln_k(float* __restrict__ h,
        const float* __restrict__ mb, const float* __restrict__ em,
        const float* __restrict__ w, const float* __restrict__ bb,
        u16* __restrict__ A2) {
    int row = blockIdx.x * 4 + (threadIdx.x >> 6);
    int lane = threadIdx.x & 63;
    int e = lane * 4;
    float* hr = h + (size_t)row * DM;
    f32x4 v = *(const f32x4*)(hr + e);
    f32x4 vm = *(const f32x4*)(mb + e);
    f32x4 ve = *(const f32x4*)(em + e);
    float s = 0.f, sq = 0.f;
    #pragma unroll
    for (int j = 0; j < 4; ++j) {
        v[j] += vm[j] + ve[j];
        s += v[j];
        sq += v[j] * v[j];
    }
    s = wave_sum(s); sq = wave_sum(sq);
    float mean = s * (1.f / DM);
    float var = sq * (1.f / DM) - mean * mean;
    float r = rsqrtf(var + 1e-5f);
    f32x4 vw = *(const f32x4*)(w + e);
    f32x4 vb = *(const f32x4*)(bb + e);
    f32x4 o;
    short4v hi4, lo4;
    #pragma unroll
    for (int j = 0; j < 4; ++j) {
        float ov = (v[j] - mean) * r * vw[j] + vb[j];
        o[j] = ov;
        u16 hi, lo; split_f16(ov, hi, lo);
        hi4[j] = (short)hi; lo4[j] = (short)lo;
    }
    *(f32x4*)(hr + e) = o;
    u16* ar = A2 + (size_t)row * 512;
    *(short4v*)(ar + e) = hi4;
    *(short4v*)(ar + 256 + e) = lo4;
}

// ---------------- causal depthwise conv (K=4) + silu on xBC -----------------
__global__ void conv_k(const float* __restrict__ zx, const float* __restrict__ cw,
                       const float* __restrict__ cb, float* __restrict__ xbc) {
    int idx = blockIdx.x * blockDim.x + threadIdx.x;
    if (idx >= M_TOT * CD) return;
    int c = idx % CD;
    int m = idx / CD;
    int t = m % T_;
    float acc = cb[c];
    #pragma unroll
    for (int k = 0; k < 4; ++k) {
        int tt = t - 3 + k;
        if (tt >= 0) acc += cw[c*4+k] * zx[(size_t)(m - (3 - k)) * DIP + DI + c];
    }
    float s = acc / (1.f + expf(-acc));
    xbc[idx] = s;
}

// ---------------- scan pass 1: chunk-local scan (dt inline) -----------------
__global__ __launch_bounds__(128) void scan1_k(const float* __restrict__ xbc,
        const float* __restrict__ zx, const float* __restrict__ dtb_in,
        const float* __restrict__ A_log, const float* __restrict__ D_skip,
        float* __restrict__ y, float* __restrict__ s_end, float* __restrict__ Pprod) {
    int c   = blockIdx.x & 7;
    int bhq = blockIdx.x >> 3;
    int b   = bhq >> 2;
    int hq  = bhq & 3;
    int h   = hq * 4 + (threadIdx.x >> 5);
    int p   = threadIdx.x & 31;
    float A  = -expf(A_log[h]);
    float Dh = D_skip[h];
    float bias = dtb_in[h];
    float s[16];
    #pragma unroll
    for (int n = 0; n < 16; ++n) s[n] = 0.f;
    float pr = 1.f;
    int base = b * T_ + c * CLEN;
    const float* row = xbc + (size_t)base * CD;
    float dtr0 = zx[(size_t)base * DIP + DI + CD + h] + bias;
    float dt = (dtr0 > 20.f) ? dtr0 : log1pf(expf(dtr0));
    float xh = row[h * HD + p];
    f32x4 Bv[4], Cv[4];
    #pragma unroll
    for (int q = 0; q < 4; ++q) {
        Bv[q] = *(const f32x4*)(row + DI + q * 4);
        Cv[q] = *(const f32x4*)(row + DI + DSZ + q * 4);
    }
    for (int t = 0; t < CLEN; ++t) {
        int m = base + t;
        int tn = (t + 1 < CLEN) ? t + 1 : t;
        const float* rown = xbc + (size_t)(base + tn) * CD;
        float dtrn = zx[(size_t)(base + tn) * DIP + DI + CD + h] + bias;
        float dt_n = (dtrn > 20.f) ? dtrn : log1pf(expf(dtrn));
        float xh_n = rown[h * HD + p];
        f32x4 Bn_[4], Cn_[4];
        #pragma unroll
        for (int q = 0; q < 4; ++q) {
            Bn_[q] = *(const f32x4*)(rown + DI + q * 4);
            Cn_[q] = *(const f32x4*)(rown + DI + DSZ + q * 4);
        }
        float dA = expf(dt * A);
        pr *= dA;
        float dtx = dt * xh;
        float ya0 = 0.f, ya1 = 0.f, ya2 = 0.f, ya3 = 0.f;
        #pragma unroll
        for (int q = 0; q < 4; ++q) {
            #pragma unroll
            for (int j = 0; j < 4; ++j) {
                int n = q * 4 + j;
                s[n] = fmaf(dA, s[n], dtx * Bv[q][j]);
                float prod = s[n] * Cv[q][j];
                if (q == 0) ya0 += prod;
                else if (q == 1) ya1 += prod;
                else if (q == 2) ya2 += prod;
                else ya3 += prod;
            }
        }
        y[(size_t)m * DI + h * HD + p] = fmaf(Dh, xh, (ya0 + ya1) + (ya2 + ya3));
        dt = dt_n; xh = xh_n;
        #pragma unroll
        for (int q = 0; q < 4; ++q) { Bv[q] = Bn_[q]; Cv[q] = Cn_[q]; }
    }
    size_t sidx = ((((size_t)b * NH + h) * NCHUNK + c) * 32 + p) * 16;
    #pragma unroll
    for (int q = 0; q < 4; ++q) {
        f32x4 v; v[0]=s[q*4]; v[1]=s[q*4+1]; v[2]=s[q*4+2]; v[3]=s[q*4+3];
        *(f32x4*)(s_end + sidx + q * 4) = v;
    }
    if (p == 0) Pprod[(b * NH + h) * NCHUNK + c] = pr;
}

// ---------------- scan pass 2: combine; s_init[c] stored into slot c-1 ------
__global__ __launch_bounds__(128) void scan2_k(float* __restrict__ S,
        const float* __restrict__ Pprod) {
    int b  = blockIdx.x >> 2;
    int hq = blockIdx.x & 3;
    int h  = hq * 4 + (threadIdx.x >> 5);
    int p  = threadIdx.x & 31;
    float s[16];
    #pragma unroll
    for (int n = 0; n < 16; ++n) s[n] = 0.f;
    size_t bh = (size_t)b * NH + h;
    for (int c = 1; c < NCHUNK; ++c) {
        float P = Pprod[bh * NCHUNK + (c - 1)];
        size_t eidx = ((bh * NCHUNK + (c - 1)) * 32 + p) * 16;
        #pragma unroll
        for (int q = 0; q < 4; ++q) {
            f32x4 e = *(const f32x4*)(S + eidx + q * 4);
            f32x4 o;
            #pragma unroll
            for (int j = 0; j < 4; ++j) {
                s[q*4+j] = fmaf(P, s[q*4+j], e[j]);
                o[j] = s[q*4+j];
            }
            *(f32x4*)(S + eidx + q * 4) = o;   // slot c-1 now holds s_init[c]
        }
    }
}

// ---------------- scan pass 3: y += cumdA * (C . s_init), dt inline ---------
__global__ __launch_bounds__(128) void scan3_k(const float* __restrict__ xbc,
        const float* __restrict__ zx, const float* __restrict__ dtb_in,
        const float* __restrict__ A_log, const float* __restrict__ S,
        float* __restrict__ y) {
    int c   = (blockIdx.x % 7) + 1;
    int bhq = blockIdx.x / 7;
    int b   = bhq >> 2;
    int hq  = bhq & 3;
    int h   = hq * 4 + (threadIdx.x >> 5);
    int p   = threadIdx.x & 31;
    float A = -expf(A_log[h]);
    float bias = dtb_in[h];
    size_t iidx = ((((size_t)b * NH + h) * NCHUNK + (c - 1)) * 32 + p) * 16;
    float si[16];
    #pragma unroll
    for (int q = 0; q < 4; ++q) {
        f32x4 v = *(const f32x4*)(S + iidx + q * 4);
        si[q*4] = v[0]; si[q*4+1] = v[1]; si[q*4+2] = v[2]; si[q*4+3] = v[3];
    }
    float cum = 1.f;
    int base = b * T_ + c * CLEN;
    for (int t = 0; t < CLEN; ++t) {
        int m = base + t;
        float dtr = zx[(size_t)m * DIP + DI + CD + h] + bias;
        float dt = (dtr > 20.f) ? dtr : log1pf(expf(dtr));
        cum *= expf(dt * A);
        const float* Cr = xbc + (size_t)m * CD + DI + DSZ;
        float dot = 0.f;
        #pragma unroll
        for (int q = 0; q < 4; ++q) {
            f32x4 Cv = *(const f32x4*)(Cr + q * 4);
            #pragma unroll
            for (int j = 0; j < 4; ++j) dot = fmaf(si[q*4+j], Cv[j], dot);
        }
        y[(size_t)m * DI + h * HD + p] += cum * dot;
    }
}

// ---------------- gated RMSNorm (wave/row of 512) -> A2 (hi|lo, K=512) ------
__global__ __launch_bounds__(256) void gate_rms_k(const float* __restrict__ y,
        const float* __restrict__ zx, const float* __restrict__ nw,
        u16* __restrict__ A2) {
    int row = blockIdx.x * 4 + (threadIdx.x >> 6);
    int lane = threadIdx.x & 63;
    int e0 = lane * 4, e1 = 256 + lane * 4;
    const float* yr = y + (size_t)row * DI;
    const float* zr = zx + (size_t)row * DIP;
    f32x4 y0 = *(const f32x4*)(yr + e0);
    f32x4 y1 = *(const f32x4*)(yr + e1);
    f32x4 z0 = *(const f32x4*)(zr + e0);
    f32x4 z1 = *(const f32x4*)(zr + e1);
    f32x4 g0, g1;
    float sq = 0.f;
    #pragma unroll
    for (int j = 0; j < 4; ++j) {
        g0[j] = y0[j] * (z0[j] / (1.f + expf(-z0[j])));
        g1[j] = y1[j] * (z1[j] / (1.f + expf(-z1[j])));
        sq += g0[j] * g0[j] + g1[j] * g1[j];
    }
    sq = wave_sum(sq);
    float r = rsqrtf(sq * (1.f / DI) + 1e-5f);
    f32x4 w0 = *(const f32x4*)(nw + e0);
    f32x4 w1 = *(const f32x4*)(nw + e1);
    u16* ar = A2 + (size_t)row * 1024;
    short4v hi4, lo4;
    #pragma unroll
    for (int j = 0; j < 4; ++j) {
        float ov = g0[j] * r * w0[j];
        u16 hi, lo; split_f16(ov, hi, lo);
        hi4[j] = (short)hi; lo4[j] = (short)lo;
    }
    *(short4v*)(ar + e0) = hi4;
    *(short4v*)(ar + 512 + e0) = lo4;
    #pragma unroll
    for (int j = 0; j < 4; ++j) {
        float ov = g1[j] * r * w1[j];
        u16 hi, lo; split_f16(ov, hi, lo);
        hi4[j] = (short)hi; lo4[j] = (short)lo;
    }
    *(short4v*)(ar + e1) = hi4;
    *(short4v*)(ar + 512 + e1) = lo4;
}

// ---------------- h = LN(c + h) (wave/row of 256) -> h + A2 (K=256) ---------
__global__ __launch_bounds__(256) void add_ln_k(float* __restrict__ h,
        const float* __restrict__ c, const float* __restrict__ w,
        const float* __restrict__ bb, u16* __restrict__ A2) {
    int row = blockIdx.x * 4 + (threadIdx.x >> 6);
    int lane = threadIdx.x & 63;
    int e = lane * 4;
    float* hr = h + (size_t)row * DM;
    const float* cr = c + (size_t)row * DM;
    f32x4 v = *(const f32x4*)(hr + e);
    f32x4 vc = *(const f32x4*)(cr + e);
    float s = 0.f, sq = 0.f;
    #pragma unroll
    for (int j = 0; j < 4; ++j) {
        v[j] += vc[j];
        s += v[j];
        sq += v[j] * v[j];
    }
    s = wave_sum(s); sq = wave_sum(sq);
    float mean = s * (1.f / DM);
    float var = sq * (1.f / DM) - mean * mean;
    float r = rsqrtf(var + 1e-5f);
    f32x4 vw = *(const f32x4*)(w + e);
    f32x4 vb = *(const f32x4*)(bb + e);
    f32x4 o;
    short4v hi4, lo4;
    #pragma unroll
    for (int j = 0; j < 4; ++j) {
        float ov = (v[j] - mean) * r * vw[j] + vb[j];
        o[j] = ov;
        u16 hi, lo; split_f16(ov, hi, lo);
        hi4[j] = (short)hi; lo4[j] = (short)lo;
    }
    *(f32x4*)(hr + e) = o;
    u16* ar = A2 + (size_t)row * 512;
    *(short4v*)(ar + e) = hi4;
    *(short4v*)(ar + 256 + e) = lo4;
}

// ---------------- mean over time -------------------------------------------
__global__ __launch_bounds__(DM) void pool_k(const float* __restrict__ h,
                                             float* __restrict__ pooled) {
    int b = blockIdx.x, d = threadIdx.x;
    float s = 0.f;
    for (int t = 0; t < T_; ++t) s += h[(size_t)(b * T_ + t) * DM + d];
    pooled[b * DM + d] = s * (1.f / T_);
}

// ---------------- head: relu(pooled@W1^T+b1)@W2^T + b2 ----------------------
__global__ __launch_bounds__(128) void head_k(const float* __restrict__ pooled,
        const float* __restrict__ w1, const float* __restrict__ b1,
        const float* __restrict__ w2, const float* __restrict__ b2,
        float* __restrict__ out) {
    int b = blockIdx.x, j = threadIdx.x;
    const float* pr = pooled + b * DM;
    float acc = b1[j];
    for (int d = 0; d < DM; ++d) acc += pr[d] * w1[j * DM + d];
    float hid = fmaxf(acc, 0.f);
    float v = hid * w2[j];
    #pragma unroll
    for (int off = 32; off > 0; off >>= 1) v += __shfl_xor(v, off);
    __shared__ float red[2];
    if ((j & 63) == 0) red[j >> 6] = v;
    __syncthreads();
    if (j == 0) out[b] = red[0] + red[1] + b2[0];
}

extern "C" void kernel_launch(void* const* d_in, const int* in_sizes, int n_in,
                              void* d_out, int out_size, void* d_ws, size_t ws_size,
                              hipStream_t stream) {
    const float* x         = (const float*)d_in[0];
    const float* emb       = (const float*)d_in[1];
    const float* sconv_w   = (const float*)d_in[2];
    const float* sconv_b   = (const float*)d_in[3];
    const float* mixer_w   = (const float*)d_in[4];
    const float* mixer_b   = (const float*)d_in[5];
    const float* enc_ln_w  = (const float*)d_in[6];
    const float* enc_ln_b  = (const float*)d_in[7];
    const float* in_proj_w = (const float*)d_in[8];
    const float* conv_w    = (const float*)d_in[9];
    const float* conv_b    = (const float*)d_in[10];
    const float* dt_bias   = (const float*)d_in[11];
    const float* A_log     = (const float*)d_in[12];
    const float* D_skip    = (const float*)d_in[13];
    const float* norm_w    = (const float*)d_in[14];
    const float* out_proj_w= (const float*)d_in[15];
    const float* ln_w      = (const float*)d_in[16];
    const float* ln_b      = (const float*)d_in[17];
    const float* head1_w   = (const float*)d_in[18];
    const float* head1_b   = (const float*)d_in[19];
    const float* head2_w   = (const float*)d_in[20];
    const float* head2_b   = (const float*)d_in[21];
    float* out = (float*)d_out;

    float* ws  = (float*)d_ws;
    float* h   = ws;                          // M*DM
    float* zx  = h   + (size_t)M_TOT * DM;    // M*DIP
    float* xbc = zx  + (size_t)M_TOT * DIP;   // M*CD
    float* y   = xbc + (size_t)M_TOT * CD;    // M*DI
    float* em  = y   + (size_t)M_TOT * DI;    // 256
    float* pooled = em + 256;                 // 16,384
    u16* A2  = (u16*)(pooled + 16384);        // 12800*1024 u16 (max, out_proj)
    u16* B2e = A2 + (size_t)12800 * 1024;     // 256*384
    u16* B2i = B2e + (size_t)256 * 384;       // 4*1152*512
    u16* B2o = B2i + (size_t)4 * 1152 * 512;  // 4*256*1024

    // scan scratch aliases A2 (dead between gemm(in_proj) and gate_rms)
    float* S     = (float*)A2;                     // 64*16*8*512 floats = 16.8MB
    float* Pprod = S + (size_t)B_*NH*NCHUNK*512;   // 8192 floats

    // ---- one-time packs ----
    emb_mean_k<<<1, DM, 0, stream>>>(emb, em);
    pack_b2_k<<<(256 * KENC + 255) / 256, 256, 0, stream>>>(
        mixer_w, B2e, 1, DM, DM, NCH_, KENC);
    pack_b2_k<<<(4 * 1152 * DM + 255) / 256, 256, 0, stream>>>(
        in_proj_w, B2i, 4, DIP, 1152, DM, DM);
    pack_b2_k<<<(4 * 256 * DI + 255) / 256, 256, 0, stream>>>(
        out_proj_w, B2o, 4, DM, DM, DI, DI);

    // ---- encoder ----
    xsA2_k<<<(M_TOT * KENC + 255) / 256, 256, 0, stream>>>(x, sconv_w, sconv_b, A2);
    gemm_mfma<<<2 * 100, 256, 0, stream>>>(A2, B2e, h, 2 * KENC, DM, DM, 2);
    enc_ln_k<<<M_TOT / 4, 256, 0, stream>>>(h, mixer_b, em, enc_ln_w, enc_ln_b, A2);

    for (int l = 0; l < 4; ++l) {
        // in_proj: K=256 -> K2=512, N=1072 (pad 1152)
        gemm_mfma<<<9 * 100, 256, 0, stream>>>(
            A2, B2i + (size_t)l * 1152 * 512, zx, 512, DIP, DIP, 9);

        conv_k<<<(M_TOT * CD + 255) / 256, 256, 0, stream>>>(
            zx, conv_w + l * CD * 4, conv_b + l * CD, xbc);

        scan1_k<<<B_ * 4 * NCHUNK, 128, 0, stream>>>(
            xbc, zx, dt_bias + l * NH, A_log + l * NH, D_skip + l * NH, y, S, Pprod);
        scan2_k<<<B_ * 4, 128, 0, stream>>>(S, Pprod);
        scan3_k<<<B_ * 4 * (NCHUNK - 1), 128, 0, stream>>>(
            xbc, zx, dt_bias + l * NH, A_log + l * NH, S, y);

        gate_rms_k<<<M_TOT / 4, 256, 0, stream>>>(y, zx, norm_w + l * DI, A2);

        // out_proj: K=512 -> K2=1024, N=256
        gemm_mfma<<<2 * 100, 256, 0, stream>>>(
            A2, B2o + (size_t)l * 256 * 1024, zx, 1024, DM, DM, 2);

        add_ln_k<<<M_TOT / 4, 256, 0, stream>>>(h, zx, ln_w + l * DM, ln_b + l * DM, A2);
    }

    pool_k<<<B_, DM, 0, stream>>>(h, pooled);
    head_k<<<B_, 128, 0, stream>>>(pooled, head1_w, head1_b, head2_w, head2_b, out);
}

// Round 7
// 675.795 us; speedup vs baseline: 1.2556x; 1.2556x over previous
//
#include <hip/hip_runtime.h>
#include <math.h>

#define B_   64
#define T_   200
#define DM   256
#define DI   512
#define NH   16
#define HD   32
#define DSZ  16
#define CD   544
#define DIP  1072
#define M_TOT (B_*T_)   // 12800
#define NCH_ 129
#define KENC 192        // encoder K padded (129 -> 192, 2*192 = 384 = 6*64)
#define NCHUNK 10
#define CLEN  20        // 200 / 10

typedef unsigned short u16;
typedef unsigned int u32;
typedef _Float16 f16;
typedef __attribute__((ext_vector_type(8))) _Float16 half8;  // 8 f16 (4 VGPRs)
typedef __attribute__((ext_vector_type(4))) short short4v;   // 4 u16
typedef __attribute__((ext_vector_type(4))) float f32x4;
typedef __attribute__((ext_vector_type(2))) float f32x2;

// ---------------- helpers ----------------------------------------------------
__device__ __forceinline__ float wave_sum(float v) {
    #pragma unroll
    for (int off = 32; off > 0; off >>= 1) v += __shfl_xor(v, off);
    return v;
}
__device__ __forceinline__ void split_f16(float a, u16& hi, u16& lo) {
    f16 h = (f16)a;
    f16 l = (f16)(a - (float)h);
    hi = __builtin_bit_cast(u16, h);
    lo = __builtin_bit_cast(u16, l);
}
__device__ __forceinline__ u16 f16bits(float a) {
    f16 h = (f16)a;
    return __builtin_bit_cast(u16, h);
}

// ---------------- emb mean over channels ------------------------------------
__global__ void emb_mean_k(const float* __restrict__ emb, float* __restrict__ em) {
    int d = threadIdx.x;
    float s = 0.f;
    for (int c = 0; c < NCH_; ++c) s += emb[c * DM + d];
    em[d] = s * (1.f / NCH_);
}

// ---------------- encoder dwconv (K=3) -> A2 [M x 2*KENC] (hi|lo) -----------
__global__ void xsA2_k(const float* __restrict__ x, const float* __restrict__ w,
                       const float* __restrict__ b, u16* __restrict__ A2) {
    int idx = blockIdx.x * blockDim.x + threadIdx.x;
    if (idx >= M_TOT * KENC) return;
    int c = idx % KENC;
    int m = idx / KENC;
    float acc = 0.f;
    if (c < NCH_) {
        int t = m % T_;
        int bb = m / T_;
        const float* xr = x + (size_t)(bb * NCH_ + c) * T_;
        acc = b[c];
        if (t > 0)      acc += w[c*3+0] * xr[t-1];
        acc += w[c*3+1] * xr[t];
        if (t < T_-1)   acc += w[c*3+2] * xr[t+1];
    }
    u16 hi, lo; split_f16(acc, hi, lo);
    u16* row = A2 + (size_t)m * (2*KENC);
    row[c] = hi; row[KENC + c] = lo;
}

// ---------------- pack weights fp32 -> f16 [hi | hi], L layers --------------
__global__ void pack_b2_k(const float* __restrict__ W, u16* __restrict__ B2,
                          int L, int N, int Npad, int Kreal, int K) {
    int idx = blockIdx.x * blockDim.x + threadIdx.x;
    if (idx >= L * Npad * K) return;
    int k = idx % K;
    int n = (idx / K) % Npad;
    int l = idx / (K * Npad);
    u16 hi = 0;
    if (n < N && k < Kreal)
        hi = f16bits(W[((size_t)l * N + n) * Kreal + k]);
    u16* row = B2 + ((size_t)l * Npad + n) * 2 * K;
    row[k] = hi;
    row[K + k] = hi;
}

// ---------------- MFMA f16 GEMM: 128x128 tile, XCD swizzle ------------------
__global__ __launch_bounds__(256) void gemm_mfma(const u16* __restrict__ A2,
                                                 const u16* __restrict__ B2,
                                                 float* __restrict__ C,
                                                 int K2, int ldc, int Nreal,
                                                 int nbx) {
    __shared__ u16 As[128 * 64];
    __shared__ u16 Bs[128 * 64];
    int nwg = gridDim.x;
    int lin = blockIdx.x;
    int q = nwg >> 3, r = nwg & 7;
    int xcd = lin & 7, idx = lin >> 3;
    int wg = ((xcd < r) ? xcd * (q + 1) : r * (q + 1) + (xcd - r) * q) + idx;
    int bx = wg % nbx, by = wg / nbx;

    int tid = threadIdx.x;
    int lane = tid & 63;
    int wave = tid >> 6;
    int wr = wave >> 1;
    int wc = wave & 1;
    int bm = by * 128;
    int bn = bx * 128;

    f32x4 acc[4][4] = {};
    const size_t ldA = (size_t)K2 * 2;

    for (int k0 = 0; k0 < K2; k0 += 64) {
        #pragma unroll
        for (int c = 0; c < 4; ++c) {
            int o = c * 4096 + tid * 16;
            int row = o >> 7;
            int slot = (o >> 4) & 7;
            int sslot = slot ^ (row & 7);
            const char* src = (const char*)A2 + (size_t)(bm + row) * ldA
                              + (size_t)k0 * 2 + sslot * 16;
            __builtin_amdgcn_global_load_lds(
                (const __attribute__((address_space(1))) u32*)src,
                (__attribute__((address_space(3))) u32*)((char*)As + o),
                16, 0, 0);
        }
        #pragma unroll
        for (int c = 0; c < 4; ++c) {
            int o = c * 4096 + tid * 16;
            int row = o >> 7;
            int slot = (o >> 4) & 7;
            int sslot = slot ^ (row & 7);
            const char* src = (const char*)B2 + (size_t)(bn + row) * ldA
                              + (size_t)k0 * 2 + sslot * 16;
            __builtin_amdgcn_global_load_lds(
                (const __attribute__((address_space(1))) u32*)src,
                (__attribute__((address_space(3))) u32*)((char*)Bs + o),
                16, 0, 0);
        }
        __syncthreads();
        #pragma unroll
        for (int kk = 0; kk < 2; ++kk) {
            int lslot = kk * 4 + (lane >> 4);
            half8 afr[4], bfr[4];
            #pragma unroll
            for (int n = 0; n < 4; ++n) {
                int row = wc * 64 + n * 16 + (lane & 15);
                int pslot = lslot ^ (row & 7);
                bfr[n] = *(const half8*)((const char*)Bs + row * 128 + pslot * 16);
            }
            #pragma unroll
            for (int m = 0; m < 4; ++m) {
                int row = wr * 64 + m * 16 + (lane & 15);
                int pslot = lslot ^ (row & 7);
                afr[m] = *(const half8*)((const char*)As + row * 128 + pslot * 16);
            }
            #pragma unroll
            for (int m = 0; m < 4; ++m)
                #pragma unroll
                for (int n = 0; n < 4; ++n)
                    acc[m][n] = __builtin_amdgcn_mfma_f32_16x16x32_f16(
                        afr[m], bfr[n], acc[m][n], 0, 0, 0);
        }
        __syncthreads();
    }

    int crow0 = bm + wr * 64;
    int ccol0 = bn + wc * 64;
    #pragma unroll
    for (int m = 0; m < 4; ++m) {
        #pragma unroll
        for (int n = 0; n < 4; ++n) {
            int col = ccol0 + n * 16 + (lane & 15);
            if (col < Nreal) {
                #pragma unroll
                for (int j = 0; j < 4; ++j) {
                    int rrow = crow0 + m * 16 + (lane >> 4) * 4 + j;
                    C[(size_t)rrow * ldc + col] = acc[m][n][j];
                }
            }
        }
    }
}

// ---------------- MFMA f16 GEMM: 128x64 tile (small-N shapes) ---------------
__global__ __launch_bounds__(256) void gemm_mfma_n64(const u16* __restrict__ A2,
                                                     const u16* __restrict__ B2,
                                                     float* __restrict__ C,
                                                     int K2, int ldc, int Nreal,
                                                     int nbx) {
    __shared__ u16 As[128 * 64];
    __shared__ u16 Bs[64 * 64];
    int nwg = gridDim.x;
    int lin = blockIdx.x;
    int q = nwg >> 3, r = nwg & 7;
    int xcd = lin & 7, idx = lin >> 3;
    int wg = ((xcd < r) ? xcd * (q + 1) : r * (q + 1) + (xcd - r) * q) + idx;
    int bx = wg % nbx, by = wg / nbx;

    int tid = threadIdx.x;
    int lane = tid & 63;
    int wave = tid >> 6;
    int wr = wave >> 1;
    int wc = wave & 1;
    int bm = by * 128;
    int bn = bx * 64;

    f32x4 acc[4][2] = {};
    const size_t ldA = (size_t)K2 * 2;

    for (int k0 = 0; k0 < K2; k0 += 64) {
        #pragma unroll
        for (int c = 0; c < 4; ++c) {
            int o = c * 4096 + tid * 16;
            int row = o >> 7;
            int slot = (o >> 4) & 7;
            int sslot = slot ^ (row & 7);
            const char* src = (const char*)A2 + (size_t)(bm + row) * ldA
                              + (size_t)k0 * 2 + sslot * 16;
            __builtin_amdgcn_global_load_lds(
                (const __attribute__((address_space(1))) u32*)src,
                (__attribute__((address_space(3))) u32*)((char*)As + o),
                16, 0, 0);
        }
        #pragma unroll
        for (int c = 0; c < 2; ++c) {
            int o = c * 4096 + tid * 16;
            int row = o >> 7;
            int slot = (o >> 4) & 7;
            int sslot = slot ^ (row & 7);
            const char* src = (const char*)B2 + (size_t)(bn + row) * ldA
                              + (size_t)k0 * 2 + sslot * 16;
            __builtin_amdgcn_global_load_lds(
                (const __attribute__((address_space(1))) u32*)src,
                (__attribute__((address_space(3))) u32*)((char*)Bs + o),
                16, 0, 0);
        }
        __syncthreads();
        #pragma unroll
        for (int kk = 0; kk < 2; ++kk) {
            int lslot = kk * 4 + (lane >> 4);
            half8 bfr[2];
            #pragma unroll
            for (int n = 0; n < 2; ++n) {
                int row = wc * 32 + n * 16 + (lane & 15);
                int pslot = lslot ^ (row & 7);
                bfr[n] = *(const half8*)((const char*)Bs + row * 128 + pslot * 16);
            }
            #pragma unroll
            for (int m = 0; m < 4; ++m) {
                int row = wr * 64 + m * 16 + (lane & 15);
                int pslot = lslot ^ (row & 7);
                half8 afr = *(const half8*)((const char*)As + row * 128 + pslot * 16);
                acc[m][0] = __builtin_amdgcn_mfma_f32_16x16x32_f16(afr, bfr[0], acc[m][0], 0, 0, 0);
                acc[m][1] = __builtin_amdgcn_mfma_f32_16x16x32_f16(afr, bfr[1], acc[m][1], 0, 0, 0);
            }
        }
        __syncthreads();
    }

    int crow0 = bm + wr * 64;
    int ccol0 = bn + wc * 32;
    #pragma unroll
    for (int m = 0; m < 4; ++m) {
        #pragma unroll
        for (int n = 0; n < 2; ++n) {
            int col = ccol0 + n * 16 + (lane & 15);
            if (col < Nreal) {
                #pragma unroll
                for (int j = 0; j < 4; ++j) {
                    int rrow = crow0 + m * 16 + (lane >> 4) * 4 + j;
                    C[(size_t)rrow * ldc + col] = acc[m][n][j];
                }
            }
        }
    }
}

// ---------------- encoder LN (wave/row): h += mb+em; LN; write h + A2 -------
__global__ __launch_bounds__(256) void enc_ln_k(float* __restrict__ h,
        const float* __restrict__ mb, const float* __restrict__ em,
        const float* __restrict__ w, const float* __restrict__ bb,
        u16* __restrict__ A2) {
    int row = blockIdx.x * 4 + (threadIdx.x >> 6);
    int lane = threadIdx.x & 63;
    int e = lane * 4;
    float* hr = h + (size_t)row * DM;
    f32x4 v = *(const f32x4*)(hr + e);
    f32x4 vm = *(const f32x4*)(mb + e);
    f32x4 ve = *(const f32x4*)(em + e);
    float s = 0.f, sq = 0.f;
    #pragma unroll
    for (int j = 0; j < 4; ++j) {
        v[j] += vm[j] + ve[j];
        s += v[j];
        sq += v[j] * v[j];
    }
    s = wave_sum(s); sq = wave_sum(sq);
    float mean = s * (1.f / DM);
    float var = sq * (1.f / DM) - mean * mean;
    float r = rsqrtf(var + 1e-5f);
    f32x4 vw = *(const f32x4*)(w + e);
    f32x4 vb = *(const f32x4*)(bb + e);
    f32x4 o;
    short4v hi4, lo4;
    #pragma unroll
    for (int j = 0; j < 4; ++j) {
        float ov = (v[j] - mean) * r * vw[j] + vb[j];
        o[j] = ov;
        u16 hi, lo; split_f16(ov, hi, lo);
        hi4[j] = (short)hi; lo4[j] = (short)lo;
    }
    *(f32x4*)(hr + e) = o;
    u16* ar = A2 + (size_t)row * 512;
    *(short4v*)(ar + e) = hi4;
    *(short4v*)(ar + 256 + e) = lo4;
}

// ---------------- dt = softplus(dt_raw + bias); dA = exp(dt*A) --------------
__global__ void dt_k(const float* __restrict__ zx, const float* __restrict__ dtb_in,
                     const float* __restrict__ A_log,
                     float* __restrict__ dtb, float* __restrict__ dAb) {
    int idx = blockIdx.x * blockDim.x + threadIdx.x;
    if (idx >= M_TOT * NH) return;
    int h = idx % NH;
    int m = idx / NH;
    float xv = zx[(size_t)m * DIP + (DI + CD) + h] + dtb_in[h];
    float dt = (xv > 20.f) ? xv : log1pf(expf(xv));
    float A = -expf(A_log[h]);
    dtb[idx] = dt;
    dAb[idx] = expf(dt * A);
}

// ---------------- causal depthwise conv (K=4) + silu on xBC -----------------
__global__ void conv_k(const float* __restrict__ zx, const float* __restrict__ cw,
                       const float* __restrict__ cb, float* __restrict__ xbc) {
    int idx = blockIdx.x * blockDim.x + threadIdx.x;
    if (idx >= M_TOT * CD) return;
    int c = idx % CD;
    int m = idx / CD;
    int t = m % T_;
    float acc = cb[c];
    #pragma unroll
    for (int k = 0; k < 4; ++k) {
        int tt = t - 3 + k;
        if (tt >= 0) acc += cw[c*4+k] * zx[(size_t)(m - (3 - k)) * DIP + DI + c];
    }
    float s = acc / (1.f + expf(-acc));
    xbc[idx] = s;
}

// ---------------- scan pass 1: chunk-local scan (no transcendentals) --------
__global__ __launch_bounds__(128) void scan1_k(const float* __restrict__ xbc,
        const float* __restrict__ dtb, const float* __restrict__ dAb,
        const float* __restrict__ D_skip, float* __restrict__ y,
        float* __restrict__ S, float* __restrict__ Pprod) {
    int c   = blockIdx.x % NCHUNK;
    int bhq = blockIdx.x / NCHUNK;
    int b   = bhq >> 2;
    int hq  = bhq & 3;
    int h   = hq * 4 + (threadIdx.x >> 5);
    int p   = threadIdx.x & 31;
    float Dh = D_skip[h];
    float s[16];
    #pragma unroll
    for (int n = 0; n < 16; ++n) s[n] = 0.f;
    float pr = 1.f;
    int base = b * T_ + c * CLEN;
    const float* row = xbc + (size_t)base * CD;
    float dt = dtb[base * NH + h];
    float dA = dAb[base * NH + h];
    float xh = row[h * HD + p];
    f32x4 Bv[4], Cv[4];
    #pragma unroll
    for (int qq = 0; qq < 4; ++qq) {
        Bv[qq] = *(const f32x4*)(row + DI + qq * 4);
        Cv[qq] = *(const f32x4*)(row + DI + DSZ + qq * 4);
    }
    for (int t = 0; t < CLEN; ++t) {
        int m = base + t;
        int tn = (t + 1 < CLEN) ? t + 1 : t;
        const float* rown = xbc + (size_t)(base + tn) * CD;
        float dt_n = dtb[(base + tn) * NH + h];
        float dA_n = dAb[(base + tn) * NH + h];
        float xh_n = rown[h * HD + p];
        f32x4 Bn_[4], Cn_[4];
        #pragma unroll
        for (int qq = 0; qq < 4; ++qq) {
            Bn_[qq] = *(const f32x4*)(rown + DI + qq * 4);
            Cn_[qq] = *(const f32x4*)(rown + DI + DSZ + qq * 4);
        }
        pr *= dA;
        float dtx = dt * xh;
        float ya0 = 0.f, ya1 = 0.f, ya2 = 0.f, ya3 = 0.f;
        #pragma unroll
        for (int qq = 0; qq < 4; ++qq) {
            #pragma unroll
            for (int j = 0; j < 4; ++j) {
                int n = qq * 4 + j;
                s[n] = fmaf(dA, s[n], dtx * Bv[qq][j]);
                float prod = s[n] * Cv[qq][j];
                if (qq == 0) ya0 += prod;
                else if (qq == 1) ya1 += prod;
                else if (qq == 2) ya2 += prod;
                else ya3 += prod;
            }
        }
        y[(size_t)m * DI + h * HD + p] = fmaf(Dh, xh, (ya0 + ya1) + (ya2 + ya3));
        dt = dt_n; dA = dA_n; xh = xh_n;
        #pragma unroll
        for (int qq = 0; qq < 4; ++qq) { Bv[qq] = Bn_[qq]; Cv[qq] = Cn_[qq]; }
    }
    size_t sidx = ((((size_t)b * NH + h) * NCHUNK + c) * 32 + p) * 16;
    #pragma unroll
    for (int qq = 0; qq < 4; ++qq) {
        f32x4 v; v[0]=s[qq*4]; v[1]=s[qq*4+1]; v[2]=s[qq*4+2]; v[3]=s[qq*4+3];
        *(f32x4*)(S + sidx + qq * 4) = v;
    }
    if (p == 0) Pprod[(b * NH + h) * NCHUNK + c] = pr;
}

// ---------------- scan pass 2: combine; s_init[c] stored into slot c-1 ------
__global__ __launch_bounds__(128) void scan2_k(float* __restrict__ S,
        const float* __restrict__ Pprod) {
    int b  = blockIdx.x >> 2;
    int hq = blockIdx.x & 3;
    int h  = hq * 4 + (threadIdx.x >> 5);
    int p  = threadIdx.x & 31;
    float s[16];
    #pragma unroll
    for (int n = 0; n < 16; ++n) s[n] = 0.f;
    size_t bh = (size_t)b * NH + h;
    for (int c = 1; c < NCHUNK; ++c) {
        float P = Pprod[bh * NCHUNK + (c - 1)];
        size_t eidx = ((bh * NCHUNK + (c - 1)) * 32 + p) * 16;
        #pragma unroll
        for (int qq = 0; qq < 4; ++qq) {
            f32x4 e = *(const f32x4*)(S + eidx + qq * 4);
            f32x4 o;
            #pragma unroll
            for (int j = 0; j < 4; ++j) {
                s[qq*4+j] = fmaf(P, s[qq*4+j], e[j]);
                o[j] = s[qq*4+j];
            }
            *(f32x4*)(S + eidx + qq * 4) = o;   // slot c-1 now holds s_init[c]
        }
    }
}

// ---------------- scan pass 3: y += cumdA * (C . s_init) --------------------
__global__ __launch_bounds__(128) void scan3_k(const float* __restrict__ xbc,
        const float* __restrict__ dAb, const float* __restrict__ S,
        float* __restrict__ y) {
    int c   = (blockIdx.x % (NCHUNK - 1)) + 1;
    int bhq = blockIdx.x / (NCHUNK - 1);
    int b   = bhq >> 2;
    int hq  = bhq & 3;
    int h   = hq * 4 + (threadIdx.x >> 5);
    int p   = threadIdx.x & 31;
    size_t iidx = ((((size_t)b * NH + h) * NCHUNK + (c - 1)) * 32 + p) * 16;
    float si[16];
    #pragma unroll
    for (int qq = 0; qq < 4; ++qq) {
        f32x4 v = *(const f32x4*)(S + iidx + qq * 4);
        si[qq*4] = v[0]; si[qq*4+1] = v[1]; si[qq*4+2] = v[2]; si[qq*4+3] = v[3];
    }
    float cum = 1.f;
    int base = b * T_ + c * CLEN;
    for (int t = 0; t < CLEN; ++t) {
        int m = base + t;
        cum *= dAb[m * NH + h];
        const float* Cr = xbc + (size_t)m * CD + DI + DSZ;
        float dot = 0.f;
        #pragma unroll
        for (int qq = 0; qq < 4; ++qq) {
            f32x4 Cv = *(const f32x4*)(Cr + qq * 4);
            #pragma unroll
            for (int j = 0; j < 4; ++j) dot = fmaf(si[qq*4+j], Cv[j], dot);
        }
        y[(size_t)m * DI + h * HD + p] += cum * dot;
    }
}

// ---------------- gated RMSNorm (wave/row of 512) -> A2 (hi|lo, K=512) ------
__global__ __launch_bounds__(256) void gate_rms_k(const float* __restrict__ y,
        const float* __restrict__ zx, const float* __restrict__ nw,
        u16* __restrict__ A2) {
    int row = blockIdx.x * 4 + (threadIdx.x >> 6);
    int lane = threadIdx.x & 63;
    int e0 = lane * 4, e1 = 256 + lane * 4;
    const float* yr = y + (size_t)row * DI;
    const float* zr = zx + (size_t)row * DIP;
    f32x4 y0 = *(const f32x4*)(yr + e0);
    f32x4 y1 = *(const f32x4*)(yr + e1);
    f32x4 z0 = *(const f32x4*)(zr + e0);
    f32x4 z1 = *(const f32x4*)(zr + e1);
    f32x4 g0, g1;
    float sq = 0.f;
    #pragma unroll
    for (int j = 0; j < 4; ++j) {
        g0[j] = y0[j] * (z0[j] / (1.f + expf(-z0[j])));
        g1[j] = y1[j] * (z1[j] / (1.f + expf(-z1[j])));
        sq += g0[j] * g0[j] + g1[j] * g1[j];
    }
    sq = wave_sum(sq);
    float r = rsqrtf(sq * (1.f / DI) + 1e-5f);
    f32x4 w0 = *(const f32x4*)(nw + e0);
    f32x4 w1 = *(const f32x4*)(nw + e1);
    u16* ar = A2 + (size_t)row * 1024;
    short4v hi4, lo4;
    #pragma unroll
    for (int j = 0; j < 4; ++j) {
        float ov = g0[j] * r * w0[j];
        u16 hi, lo; split_f16(ov, hi, lo);
        hi4[j] = (short)hi; lo4[j] = (short)lo;
    }
    *(short4v*)(ar + e0) = hi4;
    *(short4v*)(ar + 512 + e0) = lo4;
    #pragma unroll
    for (int j = 0; j < 4; ++j) {
        float ov = g1[j] * r * w1[j];
        u16 hi, lo; split_f16(ov, hi, lo);
        hi4[j] = (short)hi; lo4[j] = (short)lo;
    }
    *(short4v*)(ar + e1) = hi4;
    *(short4v*)(ar + 512 + e1) = lo4;
}

// ---------------- h = LN(c + h) (wave/row of 256) -> h + A2 (K=256) ---------
__global__ __launch_bounds__(256) void add_ln_k(float* __restrict__ h,
        const float* __restrict__ c, const float* __restrict__ w,
        const float* __restrict__ bb, u16* __restrict__ A2) {
    int row = blockIdx.x * 4 + (threadIdx.x >> 6);
    int lane = threadIdx.x & 63;
    int e = lane * 4;
    float* hr = h + (size_t)row * DM;
    const float* cr = c + (size_t)row * DM;
    f32x4 v = *(const f32x4*)(hr + e);
    f32x4 vc = *(const f32x4*)(cr + e);
    float s = 0.f, sq = 0.f;
    #pragma unroll
    for (int j = 0; j < 4; ++j) {
        v[j] += vc[j];
        s += v[j];
        sq += v[j] * v[j];
    }
    s = wave_sum(s); sq = wave_sum(sq);
    float mean = s * (1.f / DM);
    float var = sq * (1.f / DM) - mean * mean;
    float r = rsqrtf(var + 1e-5f);
    f32x4 vw = *(const f32x4*)(w + e);
    f32x4 vb = *(const f32x4*)(bb + e);
    f32x4 o;
    short4v hi4, lo4;
    #pragma unroll
    for (int j = 0; j < 4; ++j) {
        float ov = (v[j] - mean) * r * vw[j] + vb[j];
        o[j] = ov;
        u16 hi, lo; split_f16(ov, hi, lo);
        hi4[j] = (short)hi; lo4[j] = (short)lo;
    }
    *(f32x4*)(hr + e) = o;
    u16* ar = A2 + (size_t)row * 512;
    *(short4v*)(ar + e) = hi4;
    *(short4v*)(ar + 256 + e) = lo4;
}

// ---------------- mean over time -------------------------------------------
__global__ __launch_bounds__(DM) void pool_k(const float* __restrict__ h,
                                             float* __restrict__ pooled) {
    int b = blockIdx.x, d = threadIdx.x;
    float s = 0.f;
    for (int t = 0; t < T_; ++t) s += h[(size_t)(b * T_ + t) * DM + d];
    pooled[b * DM + d] = s * (1.f / T_);
}

// ---------------- head: relu(pooled@W1^T+b1)@W2^T + b2 ----------------------
__global__ __launch_bounds__(128) void head_k(const float* __restrict__ pooled,
        const float* __restrict__ w1, const float* __restrict__ b1,
        const float* __restrict__ w2, const float* __restrict__ b2,
        float* __restrict__ out) {
    int b = blockIdx.x, j = threadIdx.x;
    const float* pr = pooled + b * DM;
    float acc = b1[j];
    for (int d = 0; d < DM; ++d) acc += pr[d] * w1[j * DM + d];
    float hid = fmaxf(acc, 0.f);
    float v = hid * w2[j];
    #pragma unroll
    for (int off = 32; off > 0; off >>= 1) v += __shfl_xor(v, off);
    __shared__ float red[2];
    if ((j & 63) == 0) red[j >> 6] = v;
    __syncthreads();
    if (j == 0) out[b] = red[0] + red[1] + b2[0];
}

extern "C" void kernel_launch(void* const* d_in, const int* in_sizes, int n_in,
                              void* d_out, int out_size, void* d_ws, size_t ws_size,
                              hipStream_t stream) {
    const float* x         = (const float*)d_in[0];
    const float* emb       = (const float*)d_in[1];
    const float* sconv_w   = (const float*)d_in[2];
    const float* sconv_b   = (const float*)d_in[3];
    const float* mixer_w   = (const float*)d_in[4];
    const float* mixer_b   = (const float*)d_in[5];
    const float* enc_ln_w  = (const float*)d_in[6];
    const float* enc_ln_b  = (const float*)d_in[7];
    const float* in_proj_w = (const float*)d_in[8];
    const float* conv_w    = (const float*)d_in[9];
    const float* conv_b    = (const float*)d_in[10];
    const float* dt_bias   = (const float*)d_in[11];
    const float* A_log     = (const float*)d_in[12];
    const float* D_skip    = (const float*)d_in[13];
    const float* norm_w    = (const float*)d_in[14];
    const float* out_proj_w= (const float*)d_in[15];
    const float* ln_w      = (const float*)d_in[16];
    const float* ln_b      = (const float*)d_in[17];
    const float* head1_w   = (const float*)d_in[18];
    const float* head1_b   = (const float*)d_in[19];
    const float* head2_w   = (const float*)d_in[20];
    const float* head2_b   = (const float*)d_in[21];
    float* out = (float*)d_out;

    float* ws  = (float*)d_ws;
    float* h   = ws;                          // M*DM
    float* zx  = h   + (size_t)M_TOT * DM;    // M*DIP
    float* xbc = zx  + (size_t)M_TOT * DIP;   // M*CD
    float* y   = xbc + (size_t)M_TOT * CD;    // M*DI
    float* dtb = y   + (size_t)M_TOT * DI;    // M*NH
    float* dAb = dtb + (size_t)M_TOT * NH;    // M*NH
    float* em  = dAb + (size_t)M_TOT * NH;    // 256
    float* pooled = em + 256;                 // 16,384
    u16* A2  = (u16*)(pooled + 16384);        // 12800*1024 u16 (max, out_proj)
    u16* B2e = A2 + (size_t)12800 * 1024;     // 256*384
    u16* B2i = B2e + (size_t)256 * 384;       // 4*1152*512
    u16* B2o = B2i + (size_t)4 * 1152 * 512;  // 4*256*1024

    // scan scratch aliases A2 (dead between gemm(in_proj) and gate_rms)
    float* S     = (float*)A2;                     // B*NH*NCHUNK*512 = 21.0 MB
    float* Pprod = S + (size_t)B_*NH*NCHUNK*512;   // 10240 floats

    // ---- one-time packs ----
    emb_mean_k<<<1, DM, 0, stream>>>(emb, em);
    pack_b2_k<<<(256 * KENC + 255) / 256, 256, 0, stream>>>(
        mixer_w, B2e, 1, DM, DM, NCH_, KENC);
    pack_b2_k<<<(4 * 1152 * DM + 255) / 256, 256, 0, stream>>>(
        in_proj_w, B2i, 4, DIP, 1152, DM, DM);
    pack_b2_k<<<(4 * 256 * DI + 255) / 256, 256, 0, stream>>>(
        out_proj_w, B2o, 4, DM, DM, DI, DI);

    // ---- encoder ----
    xsA2_k<<<(M_TOT * KENC + 255) / 256, 256, 0, stream>>>(x, sconv_w, sconv_b, A2);
    gemm_mfma_n64<<<4 * 100, 256, 0, stream>>>(A2, B2e, h, 2 * KENC, DM, DM, 4);
    enc_ln_k<<<M_TOT / 4, 256, 0, stream>>>(h, mixer_b, em, enc_ln_w, enc_ln_b, A2);

    for (int l = 0; l < 4; ++l) {
        // in_proj: K=256 -> K2=512, N=1072 (pad 1152)
        gemm_mfma<<<9 * 100, 256, 0, stream>>>(
            A2, B2i + (size_t)l * 1152 * 512, zx, 512, DIP, DIP, 9);

        dt_k<<<(M_TOT * NH + 255) / 256, 256, 0, stream>>>(
            zx, dt_bias + l * NH, A_log + l * NH, dtb, dAb);
        conv_k<<<(M_TOT * CD + 255) / 256, 256, 0, stream>>>(
            zx, conv_w + l * CD * 4, conv_b + l * CD, xbc);

        scan1_k<<<B_ * 4 * NCHUNK, 128, 0, stream>>>(
            xbc, dtb, dAb, D_skip + l * NH, y, S, Pprod);
        scan2_k<<<B_ * 4, 128, 0, stream>>>(S, Pprod);
        scan3_k<<<B_ * 4 * (NCHUNK - 1), 128, 0, stream>>>(xbc, dAb, S, y);

        gate_rms_k<<<M_TOT / 4, 256, 0, stream>>>(y, zx, norm_w + l * DI, A2);

        // out_proj: K=512 -> K2=1024, N=256
        gemm_mfma_n64<<<4 * 100, 256, 0, stream>>>(
            A2, B2o + (size_t)l * 256 * 1024, zx, 1024, DM, DM, 4);

        add_ln_k<<<M_TOT / 4, 256, 0, stream>>>(h, zx, ln_w + l * DM, ln_b + l * DM, A2);
    }

    pool_k<<<B_, DM, 0, stream>>>(h, pooled);
    head_k<<<B_, 128, 0, stream>>>(pooled, head1_w, head1_b, head2_w, head2_b, out);
}